// Round 5
// baseline (285.536 us; speedup 1.0000x reference)
//
#include <hip/hip_runtime.h>
#include <hip/hip_bf16.h>

typedef unsigned short u16;
typedef __attribute__((ext_vector_type(8))) short bf16x8;
typedef __attribute__((ext_vector_type(4))) float f32x4;

#define MFMA16(a, b, c) __builtin_amdgcn_mfma_f32_16x16x32_bf16((a), (b), (c), 0, 0, 0)

__device__ __forceinline__ u16 f2bf(float f) {
  union { float f; unsigned u; } v; v.f = f;
  unsigned r = v.u + 0x7fffu + ((v.u >> 16) & 1u);  // RNE
  return (u16)(r >> 16);
}

// pack two fp32 -> dword of 2 bf16 by truncation (1 VALU op)
__device__ __forceinline__ unsigned pk_trunc(float hi, float lo) {
  union { float f; unsigned u; } a, b; a.f = hi; b.f = lo;
  return __builtin_amdgcn_perm(a.u, b.u, 0x07060302u);
}

__device__ __forceinline__ void gload_lds16(const u16* g, u16* l) {
  __builtin_amdgcn_global_load_lds((const __attribute__((address_space(1))) void*)g,
                                   (__attribute__((address_space(3))) void*)l, 16, 0, 0);
}

// ---------------- fp32 -> bf16 convert ----------------
__global__ __launch_bounds__(256) void convert_bf16_k(const float* __restrict__ in,
                                                      u16* __restrict__ out, int n) {
  int i = (blockIdx.x * 256 + threadIdx.x) * 4;
  if (i >= n) return;
  float4 v = *(const float4*)(in + i);
  ushort4 o;
  o.x = f2bf(v.x); o.y = f2bf(v.y); o.z = f2bf(v.z); o.w = f2bf(v.w);
  *(ushort4*)(out + i) = o;
}

// ---------------- fused transposes: Wa [1024][3072] and Wp [1024][1024] -> bf16 [N][K] ----------------
__global__ __launch_bounds__(256) void transpose2_k(const float* __restrict__ Wa, u16* __restrict__ WaT,
                                                    const float* __restrict__ Wp, u16* __restrict__ WpT) {
  __shared__ float tile[64][65];
  int b = blockIdx.x;
  const float* W; u16* Wt; int N, n0, k0;
  if (b < 768) { W = Wa; Wt = WaT; N = 3072; n0 = (b % 48) * 64; k0 = (b / 48) * 64; }
  else { int c = b - 768; W = Wp; Wt = WpT; N = 1024; n0 = (c & 15) * 64; k0 = (c >> 4) * 64; }
  const int tx = threadIdx.x & 63, ty = threadIdx.x >> 6;
#pragma unroll
  for (int i = 0; i < 16; ++i)
    tile[ty + 4 * i][tx] = W[(size_t)(k0 + ty + 4 * i) * N + n0 + tx];
  __syncthreads();
#pragma unroll
  for (int i = 0; i < 16; ++i)
    Wt[(size_t)(n0 + ty + 4 * i) * 1024 + k0 + tx] = f2bf(tile[tx][ty + 4 * i]);
}

// ---------------- GEMM building blocks: 128x128 tile, BK=32, m97-style ----------------
#define GEMM_PROLOG                                                                \
  __shared__ u16 As[128 * 32];                                                     \
  __shared__ u16 Bs[128 * 32];                                                     \
  const int tid = threadIdx.x;                                                     \
  const int w = tid >> 6, lane = tid & 63;                                         \
  const int wm = w & 1, wn = w >> 1;                                               \
  const int fr = lane & 15, fg = lane >> 4;                                        \
  const int srow = lane >> 2, skof = (lane & 3) * 8;                               \
  u16* lA = As + w * 1024;                                                         \
  u16* lB = Bs + w * 1024;                                                         \
  f32x4 acc[4][4];                                                                 \
  _Pragma("unroll") for (int i = 0; i < 4; i++)                                    \
      _Pragma("unroll") for (int j = 0; j < 4; j++) acc[i][j] = (f32x4){0, 0, 0, 0};

// SWAP=1: acc = bfr x af (C^T: col=t, regs=4 consecutive n). SWAP=0: classic.
#define GEMM_KLOOP(Aptr, Btptr, SWAP)                                              \
  {                                                                                \
    const u16* gA0 = (Aptr) + (size_t)(m0 + w * 32 + srow) * 1024 + skof;          \
    const u16* gB0 = (Btptr) + (size_t)(n0 + w * 32 + srow) * 1024 + skof;         \
    for (int kt = 0; kt < 32; ++kt) {                                              \
      const int ko = kt * 32;                                                      \
      gload_lds16(gA0 + ko, lA);                                                   \
      gload_lds16(gA0 + ko + 16 * 1024, lA + 512);                                 \
      gload_lds16(gB0 + ko, lB);                                                   \
      gload_lds16(gB0 + ko + 16 * 1024, lB + 512);                                 \
      __syncthreads();                                                             \
      bf16x8 af[4], bfr[4];                                                        \
      _Pragma("unroll") for (int mb = 0; mb < 4; ++mb)                             \
          af[mb] = *(const bf16x8*)&As[(wm * 64 + mb * 16 + fr) * 32 + fg * 8];    \
      _Pragma("unroll") for (int nb = 0; nb < 4; ++nb)                             \
          bfr[nb] = *(const bf16x8*)&Bs[(wn * 64 + nb * 16 + fr) * 32 + fg * 8];   \
      _Pragma("unroll") for (int mb = 0; mb < 4; ++mb)                             \
          _Pragma("unroll") for (int nb = 0; nb < 4; ++nb)                         \
              acc[mb][nb] = (SWAP) ? MFMA16(bfr[nb], af[mb], acc[mb][nb])          \
                                   : MFMA16(af[mb], bfr[nb], acc[mb][nb]);         \
      __syncthreads();                                                             \
    }                                                                              \
  }

// ---------------- QKV GEMM (R3 form: natural 2D grid, classic epilogue) ----------------
__global__ __launch_bounds__(256) void gemm_qkv(const u16* __restrict__ A,
                                                const u16* __restrict__ Bt,
                                                const float* __restrict__ bias,
                                                u16* __restrict__ Qo, u16* __restrict__ Ko,
                                                u16* __restrict__ Vt) {
  const int m0 = blockIdx.y * 128, n0 = blockIdx.x * 128;
  GEMM_PROLOG
  GEMM_KLOOP(A, Bt, 0)
  const int which = n0 >> 10;  // block-uniform: 0=Q, 1=K, 2=V
#pragma unroll
  for (int nb = 0; nb < 4; ++nb) {
    const int n = n0 + wn * 64 + nb * 16 + fr;
    const float bs = bias[n];
    const int c = n & 1023, h = c >> 6, hd = c & 63;
#pragma unroll
    for (int mb = 0; mb < 4; ++mb) {
      const int mbase = m0 + wm * 64 + mb * 16 + fg * 4;
      const int bb = mbase >> 11;
      const int t = mbase & 2047;
      if (which == 0) {
        u16* dst = Qo + ((size_t)(bb * 16 + h) * 2048 + t) * 64 + hd;
#pragma unroll
        for (int r = 0; r < 4; ++r) dst[(size_t)r * 64] = f2bf((acc[mb][nb][r] + bs) * 0.125f);
      } else if (which == 1) {
        u16* dst = Ko + ((size_t)(bb * 16 + h) * 2048 + t) * 64 + hd;
#pragma unroll
        for (int r = 0; r < 4; ++r) dst[(size_t)r * 64] = f2bf(acc[mb][nb][r] + bs);
      } else {
        ushort4 pv;
        pv.x = f2bf(acc[mb][nb][0] + bs);
        pv.y = f2bf(acc[mb][nb][1] + bs);
        pv.z = f2bf(acc[mb][nb][2] + bs);
        pv.w = f2bf(acc[mb][nb][3] + bs);
        *(ushort4*)(Vt + ((size_t)(bb * 16 + h) * 64 + hd) * 2048 + t) = pv;
      }
    }
  }
}

// ---------------- Proj GEMM: swapped epilogue (float4 stores) ----------------
__global__ __launch_bounds__(256) void gemm_proj(const u16* __restrict__ A,
                                                 const u16* __restrict__ Bt,
                                                 const float* __restrict__ bias,
                                                 float* __restrict__ O) {
  const int id = blockIdx.x;
  const int m0 = (id >> 3) * 128, n0 = (id & 7) * 128;
  GEMM_PROLOG
  GEMM_KLOOP(A, Bt, 1)
#pragma unroll
  for (int mb = 0; mb < 4; ++mb) {
    const int tg = m0 + wm * 64 + mb * 16 + fr;
#pragma unroll
    for (int nb = 0; nb < 4; ++nb) {
      const int n = n0 + wn * 64 + nb * 16 + 4 * fg;
      const float4 b4 = *(const float4*)(bias + n);
      float4 o;
      o.x = acc[mb][nb][0] + b4.x;
      o.y = acc[mb][nb][1] + b4.y;
      o.z = acc[mb][nb][2] + b4.z;
      o.w = acc[mb][nb][3] + b4.w;
      *(float4*)(O + (size_t)tg * 1024 + n) = o;
    }
  }
}

// ---------------- Flash attention v5: 256 q/block (64/wave), K-tile 64 ----------------
// S^T = K·Q^T (no max pass), O^T = V^T·P^T. Phase-split QK/exp/Pwrite then PV.
#define PSTR 72
__global__ __launch_bounds__(256) void attn_k(const u16* __restrict__ Q,
                                              const u16* __restrict__ Kb,
                                              const u16* __restrict__ Vt,
                                              u16* __restrict__ Y) {
  __shared__ u16 Ks[64 * 72];
  __shared__ u16 Vs[64 * 72];
  __shared__ u16 Ps[4 * 64 * PSTR];
  const int L = blockIdx.x;
  const int xcd = L & 7, slot = L >> 3;
  const int bh = xcd * 8 + (slot & 7);
  const int qt = 7 - (slot >> 3);  // heavy q-tiles first (LPT)
  const int tid = threadIdx.x, w = tid >> 6, lane = tid & 63;
  const int fr = lane & 15, fg = lane >> 4;
  const u16* Qp = Q + (size_t)bh * 2048 * 64;
  const u16* Kp = Kb + (size_t)bh * 2048 * 64;
  const u16* Vp = Vt + (size_t)bh * 64 * 2048;
  const int qw = qt * 256 + w * 64;  // wave's 64 q: qw + 16g + fr

  bf16x8 qa[4][2];
#pragma unroll
  for (int g = 0; g < 4; ++g)
#pragma unroll
    for (int c = 0; c < 2; ++c)
      qa[g][c] = *(const bf16x8*)(Qp + (size_t)(qw + g * 16 + fr) * 64 + c * 32 + fg * 8);

  float li[4] = {0.f, 0.f, 0.f, 0.f};
  f32x4 ot[4][4];  // [g][d-block]; lane holds O^T[16mb+4fg+r][qw+16g+fr]
#pragma unroll
  for (int g = 0; g < 4; ++g)
#pragma unroll
    for (int mb = 0; mb < 4; ++mb) ot[g][mb] = (f32x4){0, 0, 0, 0};

  const int srow = tid >> 2, scol = (tid & 3) * 16;
  u16* Pw = Ps + w * 64 * PSTR;
  const int nk = 4 * qt + 4;
  const u16* Kg = Kp + (size_t)srow * 64 + scol;
  const u16* Vg = Vp + (size_t)srow * 2048 + scol;

  uint4 kr0 = *(const uint4*)(Kg);
  uint4 kr1 = *(const uint4*)(Kg + 8);
  uint4 vr0 = *(const uint4*)(Vg);
  uint4 vr1 = *(const uint4*)(Vg + 8);

  for (int jt = 0; jt < nk; ++jt) {
    const int k0 = jt * 64;
    if (jt) __syncthreads();
    *(uint4*)&Ks[srow * 72 + scol] = kr0;
    *(uint4*)&Ks[srow * 72 + scol + 8] = kr1;
    *(uint4*)&Vs[srow * 72 + scol] = vr0;
    *(uint4*)&Vs[srow * 72 + scol + 8] = vr1;
    __syncthreads();
    if (jt + 1 < nk) {
      const int kn = (jt + 1) * 64;
      kr0 = *(const uint4*)(Kg + (size_t)kn * 64);
      kr1 = *(const uint4*)(Kg + (size_t)kn * 64 + 8);
      vr0 = *(const uint4*)(Vg + kn);
      vr1 = *(const uint4*)(Vg + kn + 8);
    }
    if (k0 > qw + 63) continue;  // wave fully masked

    // Phase 1: S^T = K(A)·Q^T(B), exp, P-write. Lane holds S^T[k0+16nb+4fg+r][qw+16g+fr].
    bf16x8 kb[4][2];
#pragma unroll
    for (int nb = 0; nb < 4; ++nb) {
      kb[nb][0] = *(const bf16x8*)&Ks[(nb * 16 + fr) * 72 + fg * 8];
      kb[nb][1] = *(const bf16x8*)&Ks[(nb * 16 + fr) * 72 + 32 + fg * 8];
    }
    const bool needmask = (k0 + 63 > qw);
#pragma unroll
    for (int g = 0; g < 4; ++g) {
      f32x4 st[4];
#pragma unroll
      for (int nb = 0; nb < 4; ++nb) {
        f32x4 z = (f32x4){0, 0, 0, 0};
        z = MFMA16(kb[nb][0], qa[g][0], z);
        z = MFMA16(kb[nb][1], qa[g][1], z);
        st[nb] = z;
      }
      const int q = qw + g * 16 + fr;
      float rs0 = 0.f, rs1 = 0.f;
#pragma unroll
      for (int nb = 0; nb < 4; ++nb) {
        const int kcb = k0 + nb * 16 + 4 * fg;
        float p0 = __expf(st[nb][0]);
        float p1 = __expf(st[nb][1]);
        float p2 = __expf(st[nb][2]);
        float p3 = __expf(st[nb][3]);
        if (needmask) {
          p0 = (kcb + 0 > q) ? 0.f : p0;
          p1 = (kcb + 1 > q) ? 0.f : p1;
          p2 = (kcb + 2 > q) ? 0.f : p2;
          p3 = (kcb + 3 > q) ? 0.f : p3;
        }
        rs0 += p0 + p1;
        rs1 += p2 + p3;
        *(uint2*)&Pw[(g * 16 + fr) * PSTR + nb * 16 + 4 * fg] =
            make_uint2(pk_trunc(p1, p0), pk_trunc(p3, p2));
      }
      li[g] += rs0 + rs1;
    }
    // Phase 2: O^T += V^T(A)·P^T(B)
    bf16x8 vb[4][2];
#pragma unroll
    for (int mb = 0; mb < 4; ++mb) {
      vb[mb][0] = *(const bf16x8*)&Vs[(mb * 16 + fr) * 72 + fg * 8];
      vb[mb][1] = *(const bf16x8*)&Vs[(mb * 16 + fr) * 72 + 32 + fg * 8];
    }
#pragma unroll
    for (int g = 0; g < 4; ++g) {
      bf16x8 pa0 = *(const bf16x8*)&Pw[(g * 16 + fr) * PSTR + fg * 8];
      bf16x8 pa1 = *(const bf16x8*)&Pw[(g * 16 + fr) * PSTR + 32 + fg * 8];
#pragma unroll
      for (int mb = 0; mb < 4; ++mb) {
        ot[g][mb] = MFMA16(vb[mb][0], pa0, ot[g][mb]);
        ot[g][mb] = MFMA16(vb[mb][1], pa1, ot[g][mb]);
      }
    }
  }

  const int b = bh >> 4, h = bh & 15;
#pragma unroll
  for (int g = 0; g < 4; ++g) {
    float l = li[g];
    l += __shfl_xor(l, 16);
    l += __shfl_xor(l, 32);
    const float inv = 1.0f / l;
    const int t = qw + g * 16 + fr;
    u16* yrow = Y + ((size_t)b * 2048 + t) * 1024 + h * 64;
#pragma unroll
    for (int mb = 0; mb < 4; ++mb) {
      const unsigned d0 = (unsigned)f2bf(ot[g][mb][0] * inv) |
                          ((unsigned)f2bf(ot[g][mb][1] * inv) << 16);
      const unsigned d1 = (unsigned)f2bf(ot[g][mb][2] * inv) |
                          ((unsigned)f2bf(ot[g][mb][3] * inv) << 16);
      *(uint2*)&yrow[mb * 16 + fg * 4] = make_uint2(d0, d1);
    }
  }
}

extern "C" void kernel_launch(void* const* d_in, const int* in_sizes, int n_in,
                              void* d_out, int out_size, void* d_ws, size_t ws_size,
                              hipStream_t stream) {
  const float* x = (const float*)d_in[0];
  const float* Wa = (const float*)d_in[1];
  const float* ba = (const float*)d_in[2];
  const float* Wp = (const float*)d_in[3];
  const float* bp = (const float*)d_in[4];
  float* out = (float*)d_out;

  char* p = (char*)d_ws;
  u16* xb = (u16*)p;   p += (size_t)8192 * 1024 * 2;
  u16* WaT = (u16*)p;  p += (size_t)3072 * 1024 * 2;
  u16* WpT = (u16*)p;  p += (size_t)1024 * 1024 * 2;
  u16* Qb = (u16*)p;   p += (size_t)64 * 2048 * 64 * 2;
  u16* Kbuf = (u16*)p; p += (size_t)64 * 2048 * 64 * 2;
  u16* Vtb = (u16*)p;  p += (size_t)64 * 64 * 2048 * 2;
  u16* Yb = (u16*)p;   p += (size_t)8192 * 1024 * 2;

  convert_bf16_k<<<8192, 256, 0, stream>>>(x, xb, 8192 * 1024);
  transpose2_k<<<1024, 256, 0, stream>>>(Wa, WaT, Wp, WpT);
  gemm_qkv<<<dim3(24, 64), 256, 0, stream>>>(xb, WaT, ba, Qb, Kbuf, Vtb);
  attn_k<<<512, 256, 0, stream>>>(Qb, Kbuf, Vtb, Yb);
  gemm_proj<<<512, 256, 0, stream>>>(Yb, WpT, bp, out);
}

// Round 6
// 268.662 us; speedup vs baseline: 1.0628x; 1.0628x over previous
//
#include <hip/hip_runtime.h>
#include <hip/hip_bf16.h>

typedef unsigned short u16;
typedef __attribute__((ext_vector_type(8))) short bf16x8;
typedef __attribute__((ext_vector_type(4))) float f32x4;

#define MFMA16(a, b, c) __builtin_amdgcn_mfma_f32_16x16x32_bf16((a), (b), (c), 0, 0, 0)

__device__ __forceinline__ u16 f2bf(float f) {
  union { float f; unsigned u; } v; v.f = f;
  unsigned r = v.u + 0x7fffu + ((v.u >> 16) & 1u);  // RNE
  return (u16)(r >> 16);
}

// pack two fp32 -> dword of 2 bf16 by truncation (1 VALU op)
__device__ __forceinline__ unsigned pk_trunc(float hi, float lo) {
  union { float f; unsigned u; } a, b; a.f = hi; b.f = lo;
  return __builtin_amdgcn_perm(a.u, b.u, 0x07060302u);
}

__device__ __forceinline__ void gload_lds16(const u16* g, u16* l) {
  __builtin_amdgcn_global_load_lds((const __attribute__((address_space(1))) void*)g,
                                   (__attribute__((address_space(3))) void*)l, 16, 0, 0);
}

// ---------------- fp32 -> bf16 convert: 8 elems/thread ----------------
__global__ __launch_bounds__(256) void convert_bf16_k(const float* __restrict__ in,
                                                      u16* __restrict__ out, int n) {
  int i = (blockIdx.x * 256 + threadIdx.x) * 8;
  if (i >= n) return;
  float4 v0 = *(const float4*)(in + i);
  float4 v1 = *(const float4*)(in + i + 4);
  uint4 o;
  o.x = (unsigned)f2bf(v0.x) | ((unsigned)f2bf(v0.y) << 16);
  o.y = (unsigned)f2bf(v0.z) | ((unsigned)f2bf(v0.w) << 16);
  o.z = (unsigned)f2bf(v1.x) | ((unsigned)f2bf(v1.y) << 16);
  o.w = (unsigned)f2bf(v1.z) | ((unsigned)f2bf(v1.w) << 16);
  *(uint4*)(out + i) = o;
}

// ---------------- fused transposes: Wa [1024][3072] and Wp [1024][1024] -> bf16 [N][K] ----------------
__global__ __launch_bounds__(256) void transpose2_k(const float* __restrict__ Wa, u16* __restrict__ WaT,
                                                    const float* __restrict__ Wp, u16* __restrict__ WpT) {
  __shared__ float tile[64][65];
  int b = blockIdx.x;
  const float* W; u16* Wt; int N, n0, k0;
  if (b < 768) { W = Wa; Wt = WaT; N = 3072; n0 = (b % 48) * 64; k0 = (b / 48) * 64; }
  else { int c = b - 768; W = Wp; Wt = WpT; N = 1024; n0 = (c & 15) * 64; k0 = (c >> 4) * 64; }
  const int tx = threadIdx.x & 63, ty = threadIdx.x >> 6;
#pragma unroll
  for (int i = 0; i < 16; ++i)
    tile[ty + 4 * i][tx] = W[(size_t)(k0 + ty + 4 * i) * N + n0 + tx];
  __syncthreads();
#pragma unroll
  for (int i = 0; i < 16; ++i)
    Wt[(size_t)(n0 + ty + 4 * i) * 1024 + k0 + tx] = f2bf(tile[tx][ty + 4 * i]);
}

// ---------------- GEMM building blocks: 128x128 tile, BK=32, m97-style ----------------
#define GEMM_PROLOG                                                                \
  __shared__ u16 As[128 * 32];                                                     \
  __shared__ u16 Bs[128 * 32];                                                     \
  const int tid = threadIdx.x;                                                     \
  const int w = tid >> 6, lane = tid & 63;                                         \
  const int wm = w & 1, wn = w >> 1;                                               \
  const int fr = lane & 15, fg = lane >> 4;                                        \
  const int srow = lane >> 2, skof = (lane & 3) * 8;                               \
  u16* lA = As + w * 1024;                                                         \
  u16* lB = Bs + w * 1024;                                                         \
  f32x4 acc[4][4];                                                                 \
  _Pragma("unroll") for (int i = 0; i < 4; i++)                                    \
      _Pragma("unroll") for (int j = 0; j < 4; j++) acc[i][j] = (f32x4){0, 0, 0, 0};

// SWAP=1: acc = bfr x af (C^T: col=t, regs=4 consecutive n). SWAP=0: classic.
#define GEMM_KLOOP(Aptr, Btptr, SWAP)                                              \
  {                                                                                \
    const u16* gA0 = (Aptr) + (size_t)(m0 + w * 32 + srow) * 1024 + skof;          \
    const u16* gB0 = (Btptr) + (size_t)(n0 + w * 32 + srow) * 1024 + skof;         \
    for (int kt = 0; kt < 32; ++kt) {                                              \
      const int ko = kt * 32;                                                      \
      gload_lds16(gA0 + ko, lA);                                                   \
      gload_lds16(gA0 + ko + 16 * 1024, lA + 512);                                 \
      gload_lds16(gB0 + ko, lB);                                                   \
      gload_lds16(gB0 + ko + 16 * 1024, lB + 512);                                 \
      __syncthreads();                                                             \
      bf16x8 af[4], bfr[4];                                                        \
      _Pragma("unroll") for (int mb = 0; mb < 4; ++mb)                             \
          af[mb] = *(const bf16x8*)&As[(wm * 64 + mb * 16 + fr) * 32 + fg * 8];    \
      _Pragma("unroll") for (int nb = 0; nb < 4; ++nb)                             \
          bfr[nb] = *(const bf16x8*)&Bs[(wn * 64 + nb * 16 + fr) * 32 + fg * 8];   \
      _Pragma("unroll") for (int mb = 0; mb < 4; ++mb)                             \
          _Pragma("unroll") for (int nb = 0; nb < 4; ++nb)                         \
              acc[mb][nb] = (SWAP) ? MFMA16(bfr[nb], af[mb], acc[mb][nb])          \
                                   : MFMA16(af[mb], bfr[nb], acc[mb][nb]);         \
      __syncthreads();                                                             \
    }                                                                              \
  }

// ---------------- QKV GEMM (R3 form: natural 2D grid, classic epilogue) ----------------
__global__ __launch_bounds__(256) void gemm_qkv(const u16* __restrict__ A,
                                                const u16* __restrict__ Bt,
                                                const float* __restrict__ bias,
                                                u16* __restrict__ Qo, u16* __restrict__ Ko,
                                                u16* __restrict__ Vt) {
  const int m0 = blockIdx.y * 128, n0 = blockIdx.x * 128;
  GEMM_PROLOG
  GEMM_KLOOP(A, Bt, 0)
  const int which = n0 >> 10;  // block-uniform: 0=Q, 1=K, 2=V
#pragma unroll
  for (int nb = 0; nb < 4; ++nb) {
    const int n = n0 + wn * 64 + nb * 16 + fr;
    const float bs = bias[n];
    const int c = n & 1023, h = c >> 6, hd = c & 63;
#pragma unroll
    for (int mb = 0; mb < 4; ++mb) {
      const int mbase = m0 + wm * 64 + mb * 16 + fg * 4;
      const int bb = mbase >> 11;
      const int t = mbase & 2047;
      if (which == 0) {
        u16* dst = Qo + ((size_t)(bb * 16 + h) * 2048 + t) * 64 + hd;
#pragma unroll
        for (int r = 0; r < 4; ++r) dst[(size_t)r * 64] = f2bf((acc[mb][nb][r] + bs) * 0.125f);
      } else if (which == 1) {
        u16* dst = Ko + ((size_t)(bb * 16 + h) * 2048 + t) * 64 + hd;
#pragma unroll
        for (int r = 0; r < 4; ++r) dst[(size_t)r * 64] = f2bf(acc[mb][nb][r] + bs);
      } else {
        ushort4 pv;
        pv.x = f2bf(acc[mb][nb][0] + bs);
        pv.y = f2bf(acc[mb][nb][1] + bs);
        pv.z = f2bf(acc[mb][nb][2] + bs);
        pv.w = f2bf(acc[mb][nb][3] + bs);
        *(ushort4*)(Vt + ((size_t)(bb * 16 + h) * 64 + hd) * 2048 + t) = pv;
      }
    }
  }
}

// ---------------- Proj GEMM: swapped epilogue (float4 stores) ----------------
__global__ __launch_bounds__(256) void gemm_proj(const u16* __restrict__ A,
                                                 const u16* __restrict__ Bt,
                                                 const float* __restrict__ bias,
                                                 float* __restrict__ O) {
  const int id = blockIdx.x;
  const int m0 = (id >> 3) * 128, n0 = (id & 7) * 128;
  GEMM_PROLOG
  GEMM_KLOOP(A, Bt, 1)
#pragma unroll
  for (int mb = 0; mb < 4; ++mb) {
    const int tg = m0 + wm * 64 + mb * 16 + fr;
#pragma unroll
    for (int nb = 0; nb < 4; ++nb) {
      const int n = n0 + wn * 64 + nb * 16 + 4 * fg;
      const float4 b4 = *(const float4*)(bias + n);
      float4 o;
      o.x = acc[mb][nb][0] + b4.x;
      o.y = acc[mb][nb][1] + b4.y;
      o.z = acc[mb][nb][2] + b4.z;
      o.w = acc[mb][nb][3] + b4.w;
      *(float4*)(O + (size_t)tg * 1024 + n) = o;
    }
  }
}

// ---------------- Flash attention (R4/v4 form, measured best): 128 q/block (32/wave) ----------------
// S^T = K·Q^T (no max pass), O^T = V^T·P^T. PSTR=72 -> 36.9 KB LDS -> 4 blocks/CU.
#define PSTR 72
__global__ __launch_bounds__(256) void attn_k(const u16* __restrict__ Q,
                                              const u16* __restrict__ Kb,
                                              const u16* __restrict__ Vt,
                                              u16* __restrict__ Y) {
  __shared__ u16 Ks[64 * 72];
  __shared__ u16 Vs[64 * 72];
  __shared__ u16 Ps[4 * 32 * PSTR];
  const int L = blockIdx.x;
  const int xcd = L & 7, slot = L >> 3;
  const int bh = xcd * 8 + (slot & 7);
  const int qt = 15 - (slot >> 3);
  const int tid = threadIdx.x, w = tid >> 6, lane = tid & 63;
  const int fr = lane & 15, fg = lane >> 4;
  const u16* Qp = Q + (size_t)bh * 2048 * 64;
  const u16* Kp = Kb + (size_t)bh * 2048 * 64;
  const u16* Vp = Vt + (size_t)bh * 64 * 2048;
  const int qw = qt * 128 + w * 32;

  bf16x8 qa[2][2];
#pragma unroll
  for (int g = 0; g < 2; ++g)
#pragma unroll
    for (int c = 0; c < 2; ++c)
      qa[g][c] = *(const bf16x8*)(Qp + (size_t)(qw + g * 16 + fr) * 64 + c * 32 + fg * 8);

  float li[2] = {0.f, 0.f};
  f32x4 ot[2][4];
#pragma unroll
  for (int g = 0; g < 2; ++g)
#pragma unroll
    for (int mb = 0; mb < 4; ++mb) ot[g][mb] = (f32x4){0, 0, 0, 0};

  const int srow = tid >> 2, scol = (tid & 3) * 16;
  u16* Pw = Ps + w * 32 * PSTR;
  const int nk = 2 * qt + 2;
  const u16* Kg = Kp + (size_t)srow * 64 + scol;
  const u16* Vg = Vp + (size_t)srow * 2048 + scol;

  uint4 kr0 = *(const uint4*)(Kg);
  uint4 kr1 = *(const uint4*)(Kg + 8);
  uint4 vr0 = *(const uint4*)(Vg);
  uint4 vr1 = *(const uint4*)(Vg + 8);

  for (int jt = 0; jt < nk; ++jt) {
    const int k0 = jt * 64;
    if (jt) __syncthreads();
    *(uint4*)&Ks[srow * 72 + scol] = kr0;
    *(uint4*)&Ks[srow * 72 + scol + 8] = kr1;
    *(uint4*)&Vs[srow * 72 + scol] = vr0;
    *(uint4*)&Vs[srow * 72 + scol + 8] = vr1;
    __syncthreads();
    if (jt + 1 < nk) {
      const int kn = (jt + 1) * 64;
      kr0 = *(const uint4*)(Kg + (size_t)kn * 64);
      kr1 = *(const uint4*)(Kg + (size_t)kn * 64 + 8);
      vr0 = *(const uint4*)(Vg + kn);
      vr1 = *(const uint4*)(Vg + kn + 8);
    }
    if (k0 > qw + 31) continue;

    bf16x8 kb[4][2];
#pragma unroll
    for (int nb = 0; nb < 4; ++nb) {
      kb[nb][0] = *(const bf16x8*)&Ks[(nb * 16 + fr) * 72 + fg * 8];
      kb[nb][1] = *(const bf16x8*)&Ks[(nb * 16 + fr) * 72 + 32 + fg * 8];
    }
    f32x4 st[2][4];
#pragma unroll
    for (int g = 0; g < 2; ++g)
#pragma unroll
      for (int nb = 0; nb < 4; ++nb) {
        f32x4 z = (f32x4){0, 0, 0, 0};
        z = MFMA16(kb[nb][0], qa[g][0], z);
        z = MFMA16(kb[nb][1], qa[g][1], z);
        st[g][nb] = z;
      }
    const bool needmask = (k0 + 63 > qw);
#pragma unroll
    for (int g = 0; g < 2; ++g) {
      const int q = qw + g * 16 + fr;
      float rs0 = 0.f, rs1 = 0.f;
#pragma unroll
      for (int nb = 0; nb < 4; ++nb) {
        const int kcb = k0 + nb * 16 + 4 * fg;
        float p0 = __expf(st[g][nb][0]);
        float p1 = __expf(st[g][nb][1]);
        float p2 = __expf(st[g][nb][2]);
        float p3 = __expf(st[g][nb][3]);
        if (needmask) {
          p0 = (kcb + 0 > q) ? 0.f : p0;
          p1 = (kcb + 1 > q) ? 0.f : p1;
          p2 = (kcb + 2 > q) ? 0.f : p2;
          p3 = (kcb + 3 > q) ? 0.f : p3;
        }
        rs0 += p0 + p1;
        rs1 += p2 + p3;
        *(uint2*)&Pw[(g * 16 + fr) * PSTR + nb * 16 + 4 * fg] =
            make_uint2(pk_trunc(p1, p0), pk_trunc(p3, p2));
      }
      li[g] += rs0 + rs1;
    }
    bf16x8 pa[2][2];
#pragma unroll
    for (int g = 0; g < 2; ++g)
#pragma unroll
      for (int H = 0; H < 2; ++H)
        pa[g][H] = *(const bf16x8*)&Pw[(g * 16 + fr) * PSTR + H * 32 + fg * 8];
#pragma unroll
    for (int mb = 0; mb < 4; ++mb) {
      bf16x8 vb0 = *(const bf16x8*)&Vs[(mb * 16 + fr) * 72 + fg * 8];
      bf16x8 vb1 = *(const bf16x8*)&Vs[(mb * 16 + fr) * 72 + 32 + fg * 8];
#pragma unroll
      for (int g = 0; g < 2; ++g) {
        ot[g][mb] = MFMA16(vb0, pa[g][0], ot[g][mb]);
        ot[g][mb] = MFMA16(vb1, pa[g][1], ot[g][mb]);
      }
    }
  }

  const int b = bh >> 4, h = bh & 15;
#pragma unroll
  for (int g = 0; g < 2; ++g) {
    float l = li[g];
    l += __shfl_xor(l, 16);
    l += __shfl_xor(l, 32);
    const float inv = 1.0f / l;
    const int t = qw + g * 16 + fr;
    u16* yrow = Y + ((size_t)b * 2048 + t) * 1024 + h * 64;
#pragma unroll
    for (int mb = 0; mb < 4; ++mb) {
      const unsigned d0 = (unsigned)f2bf(ot[g][mb][0] * inv) |
                          ((unsigned)f2bf(ot[g][mb][1] * inv) << 16);
      const unsigned d1 = (unsigned)f2bf(ot[g][mb][2] * inv) |
                          ((unsigned)f2bf(ot[g][mb][3] * inv) << 16);
      *(uint2*)&yrow[mb * 16 + fg * 4] = make_uint2(d0, d1);
    }
  }
}

extern "C" void kernel_launch(void* const* d_in, const int* in_sizes, int n_in,
                              void* d_out, int out_size, void* d_ws, size_t ws_size,
                              hipStream_t stream) {
  const float* x = (const float*)d_in[0];
  const float* Wa = (const float*)d_in[1];
  const float* ba = (const float*)d_in[2];
  const float* Wp = (const float*)d_in[3];
  const float* bp = (const float*)d_in[4];
  float* out = (float*)d_out;

  char* p = (char*)d_ws;
  u16* xb = (u16*)p;   p += (size_t)8192 * 1024 * 2;
  u16* WaT = (u16*)p;  p += (size_t)3072 * 1024 * 2;
  u16* WpT = (u16*)p;  p += (size_t)1024 * 1024 * 2;
  u16* Qb = (u16*)p;   p += (size_t)64 * 2048 * 64 * 2;
  u16* Kbuf = (u16*)p; p += (size_t)64 * 2048 * 64 * 2;
  u16* Vtb = (u16*)p;  p += (size_t)64 * 64 * 2048 * 2;
  u16* Yb = (u16*)p;   p += (size_t)8192 * 1024 * 2;

  convert_bf16_k<<<4096, 256, 0, stream>>>(x, xb, 8192 * 1024);
  transpose2_k<<<1024, 256, 0, stream>>>(Wa, WaT, Wp, WpT);
  gemm_qkv<<<dim3(24, 64), 256, 0, stream>>>(xb, WaT, ba, Qb, Kbuf, Vtb);
  attn_k<<<1024, 256, 0, stream>>>(Qb, Kbuf, Vtb, Yb);
  gemm_proj<<<512, 256, 0, stream>>>(Yb, WpT, bp, out);
}